// Round 5
// baseline (499.407 us; speedup 1.0000x reference)
//
#include <hip/hip_runtime.h>

// DiceCoeffMetric: per-(b,c) {dot(prd,tgt), sum(prd), sum(tgt)} over 1024x1024 fp32,
// dice = (2*inter+eps)/(sum_p+sum_t+eps), mean over batch -> (C,) fp32.
// Memory-bound: 512 MB read. R5: plain cached loads (drop nontemporal),
// 8 loads in flight (4/array), wave-contiguous 1KB runs, low VGPR for occupancy.

#define HW   (1024 * 1024)
#define NB   16
#define NC   4
#define NBC  (NB * NC)      // 64 (b,c) slices
#define BPS  64             // blocks per slice
#define TPB  256
#define NBLK (NBC * BPS)    // 4096 partial slots
#define EPSF 1e-6f

typedef float vf4 __attribute__((ext_vector_type(4)));

#define DOT4(a, b)  ((a).x * (b).x + (a).y * (b).y + (a).z * (b).z + (a).w * (b).w)
#define SUM4(a)     ((a).x + (a).y + (a).z + (a).w)

__global__ __launch_bounds__(TPB) void dice_partial_kernel(
        const float* __restrict__ prd,
        const float* __restrict__ tgt,
        float* __restrict__ ws) {
    const int bc   = blockIdx.y;
    const int wave = threadIdx.x >> 6;
    const int lane = threadIdx.x & 63;

    // slice = 262144 float4; block = 4096 float4 (64KB); wave = 1024 float4 (16KB)
    const size_t base = (size_t)bc * (HW / 4) + (size_t)blockIdx.x * 4096
                      + (size_t)wave * 1024 + lane;
    const vf4* __restrict__ p4 = (const vf4*)prd + base;
    const vf4* __restrict__ t4 = (const vf4*)tgt + base;

    float i0 = 0.0f, i1 = 0.0f, sp0 = 0.0f, sp1 = 0.0f, st0 = 0.0f, st1 = 0.0f;

    // 16 float4 per thread per array: 4 stages of 4+4 loads in flight.
    #pragma unroll
    for (int h = 0; h < 4; ++h) {
        const int o = h * 256;   // 4 runs of 64 float4 each per stage
        vf4 a0 = p4[o];
        vf4 b0 = t4[o];
        vf4 a1 = p4[o + 64];
        vf4 b1 = t4[o + 64];
        vf4 a2 = p4[o + 128];
        vf4 b2 = t4[o + 128];
        vf4 a3 = p4[o + 192];
        vf4 b3 = t4[o + 192];

        i0  += DOT4(a0, b0) + DOT4(a2, b2);
        i1  += DOT4(a1, b1) + DOT4(a3, b3);
        sp0 += SUM4(a0) + SUM4(a2);
        sp1 += SUM4(a1) + SUM4(a3);
        st0 += SUM4(b0) + SUM4(b2);
        st1 += SUM4(b1) + SUM4(b3);
    }

    float inter = i0 + i1, sp = sp0 + sp1, st = st0 + st1;

    // wave-64 reduce
    #pragma unroll
    for (int off = 32; off > 0; off >>= 1) {
        inter += __shfl_down(inter, off);
        sp    += __shfl_down(sp, off);
        st    += __shfl_down(st, off);
    }

    __shared__ float s[3][TPB / 64];
    if (lane == 0) {
        s[0][wave] = inter;
        s[1][wave] = sp;
        s[2][wave] = st;
    }
    __syncthreads();
    if (threadIdx.x == 0) {
        const int slot = bc * BPS + blockIdx.x;   // unique per block
        ws[0 * NBLK + slot] = s[0][0] + s[0][1] + s[0][2] + s[0][3];
        ws[1 * NBLK + slot] = s[1][0] + s[1][1] + s[1][2] + s[1][3];
        ws[2 * NBLK + slot] = s[2][0] + s[2][1] + s[2][2] + s[2][3];
    }
}

__global__ void dice_final_kernel(const float* __restrict__ ws,
                                  float* __restrict__ out) {
    __shared__ float dice[NBC];
    const int bc = threadIdx.x;
    if (bc < NBC) {
        float inter = 0.0f, sp = 0.0f, st = 0.0f;
        #pragma unroll 8
        for (int k = 0; k < BPS; ++k) {
            const int slot = bc * BPS + k;
            inter += ws[0 * NBLK + slot];
            sp    += ws[1 * NBLK + slot];
            st    += ws[2 * NBLK + slot];
        }
        dice[bc] = (2.0f * inter + EPSF) / (sp + st + EPSF);
    }
    __syncthreads();
    if (bc < NC) {
        float s = 0.0f;
        #pragma unroll
        for (int b = 0; b < NB; ++b) s += dice[b * NC + bc];
        out[bc] = s / (float)NB;
    }
}

extern "C" void kernel_launch(void* const* d_in, const int* in_sizes, int n_in,
                              void* d_out, int out_size, void* d_ws, size_t ws_size,
                              hipStream_t stream) {
    const float* prd = (const float*)d_in[0];
    const float* tgt = (const float*)d_in[1];
    float* out = (float*)d_out;
    float* ws  = (float*)d_ws;   // 3 * 4096 floats of per-block partials

    dice_partial_kernel<<<dim3(BPS, NBC), TPB, 0, stream>>>(prd, tgt, ws);
    dice_final_kernel<<<1, 64, 0, stream>>>(ws, out);
}

// Round 6
// 471.355 us; speedup vs baseline: 1.0595x; 1.0595x over previous
//
#include <hip/hip_runtime.h>

// DiceCoeffMetric: per-(b,c) {dot(prd,tgt), sum(prd), sum(tgt)} over 1024x1024 fp32,
// dice = (2*inter+eps)/(sum_p+sum_t+eps), mean over batch -> (C,) fp32.
// Memory-bound: 512 MB pure read. R6: R4 structure (wave-contiguous 1KB runs,
// 16 loads in flight/stage) but loads bypass L1+L2 via inline asm
// "global_load_dwordx4 ... off sc0 sc1 nt" (builtin nontemporal only emits nt).
// Manual s_waitcnt vmcnt(0) + sched_barrier(0) per rule #18.

#define HW   (1024 * 1024)
#define NB   16
#define NC   4
#define NBC  (NB * NC)      // 64 (b,c) slices
#define BPS  64             // blocks per slice
#define TPB  256
#define NBLK (NBC * BPS)    // 4096 partial slots
#define EPSF 1e-6f

typedef float vf4 __attribute__((ext_vector_type(4)));

#define DOT4(a, b)  ((a).x * (b).x + (a).y * (b).y + (a).z * (b).z + (a).w * (b).w)
#define SUM4(a)     ((a).x + (a).y + (a).z + (a).w)

__device__ __forceinline__ vf4 ld_stream(const vf4* p) {
    vf4 r;
    asm volatile("global_load_dwordx4 %0, %1, off sc0 sc1 nt"
                 : "=v"(r)
                 : "v"(p));
    return r;
}

__global__ __launch_bounds__(TPB) void dice_partial_kernel(
        const float* __restrict__ prd,
        const float* __restrict__ tgt,
        float* __restrict__ ws) {
    const int bc   = blockIdx.y;
    const int wave = threadIdx.x >> 6;
    const int lane = threadIdx.x & 63;

    // slice = 262144 float4; block = 4096 float4 (64KB); wave = 1024 float4 (16KB)
    const size_t base = (size_t)bc * (HW / 4) + (size_t)blockIdx.x * 4096
                      + (size_t)wave * 1024 + lane;
    const vf4* __restrict__ p4 = (const vf4*)prd + base;
    const vf4* __restrict__ t4 = (const vf4*)tgt + base;

    float i0 = 0.0f, i1 = 0.0f, sp0 = 0.0f, sp1 = 0.0f, st0 = 0.0f, st1 = 0.0f;

    // 16 float4 per thread per array: 2 stages of 8+8 loads in flight.
    #pragma unroll
    for (int h = 0; h < 2; ++h) {
        const int o = h * 512;   // 8 runs of 64 float4 each
        vf4 a0 = ld_stream(p4 + o);
        vf4 a1 = ld_stream(p4 + o + 64);
        vf4 a2 = ld_stream(p4 + o + 128);
        vf4 a3 = ld_stream(p4 + o + 192);
        vf4 a4 = ld_stream(p4 + o + 256);
        vf4 a5 = ld_stream(p4 + o + 320);
        vf4 a6 = ld_stream(p4 + o + 384);
        vf4 a7 = ld_stream(p4 + o + 448);
        vf4 b0 = ld_stream(t4 + o);
        vf4 b1 = ld_stream(t4 + o + 64);
        vf4 b2 = ld_stream(t4 + o + 128);
        vf4 b3 = ld_stream(t4 + o + 192);
        vf4 b4 = ld_stream(t4 + o + 256);
        vf4 b5 = ld_stream(t4 + o + 320);
        vf4 b6 = ld_stream(t4 + o + 384);
        vf4 b7 = ld_stream(t4 + o + 448);

        // All 16 loads are in flight; wait for data, then fence the scheduler
        // so no dependent VALU hoists above the wait (asm outputs look "ready"
        // to the compiler at issue time).
        asm volatile("s_waitcnt vmcnt(0)" ::: "memory");
        __builtin_amdgcn_sched_barrier(0);

        i0  += DOT4(a0, b0) + DOT4(a2, b2) + DOT4(a4, b4) + DOT4(a6, b6);
        i1  += DOT4(a1, b1) + DOT4(a3, b3) + DOT4(a5, b5) + DOT4(a7, b7);
        sp0 += SUM4(a0) + SUM4(a2) + SUM4(a4) + SUM4(a6);
        sp1 += SUM4(a1) + SUM4(a3) + SUM4(a5) + SUM4(a7);
        st0 += SUM4(b0) + SUM4(b2) + SUM4(b4) + SUM4(b6);
        st1 += SUM4(b1) + SUM4(b3) + SUM4(b5) + SUM4(b7);
    }

    float inter = i0 + i1, sp = sp0 + sp1, st = st0 + st1;

    // wave-64 reduce
    #pragma unroll
    for (int off = 32; off > 0; off >>= 1) {
        inter += __shfl_down(inter, off);
        sp    += __shfl_down(sp, off);
        st    += __shfl_down(st, off);
    }

    __shared__ float s[3][TPB / 64];
    if (lane == 0) {
        s[0][wave] = inter;
        s[1][wave] = sp;
        s[2][wave] = st;
    }
    __syncthreads();
    if (threadIdx.x == 0) {
        const int slot = bc * BPS + blockIdx.x;   // unique per block
        ws[0 * NBLK + slot] = s[0][0] + s[0][1] + s[0][2] + s[0][3];
        ws[1 * NBLK + slot] = s[1][0] + s[1][1] + s[1][2] + s[1][3];
        ws[2 * NBLK + slot] = s[2][0] + s[2][1] + s[2][2] + s[2][3];
    }
}

__global__ void dice_final_kernel(const float* __restrict__ ws,
                                  float* __restrict__ out) {
    __shared__ float dice[NBC];
    const int bc = threadIdx.x;
    if (bc < NBC) {
        float inter = 0.0f, sp = 0.0f, st = 0.0f;
        #pragma unroll 8
        for (int k = 0; k < BPS; ++k) {
            const int slot = bc * BPS + k;
            inter += ws[0 * NBLK + slot];
            sp    += ws[1 * NBLK + slot];
            st    += ws[2 * NBLK + slot];
        }
        dice[bc] = (2.0f * inter + EPSF) / (sp + st + EPSF);
    }
    __syncthreads();
    if (bc < NC) {
        float s = 0.0f;
        #pragma unroll
        for (int b = 0; b < NB; ++b) s += dice[b * NC + bc];
        out[bc] = s / (float)NB;
    }
}

extern "C" void kernel_launch(void* const* d_in, const int* in_sizes, int n_in,
                              void* d_out, int out_size, void* d_ws, size_t ws_size,
                              hipStream_t stream) {
    const float* prd = (const float*)d_in[0];
    const float* tgt = (const float*)d_in[1];
    float* out = (float*)d_out;
    float* ws  = (float*)d_ws;   // 3 * 4096 floats of per-block partials

    dice_partial_kernel<<<dim3(BPS, NBC), TPB, 0, stream>>>(prd, tgt, ws);
    dice_final_kernel<<<1, 64, 0, stream>>>(ws, out);
}